// Round 18
// baseline (13711.684 us; speedup 1.0000x reference)
//
#include <hip/hip_runtime.h>

// ---------------------------------------------------------------------------
// 2-layer LSTM encoder, B=128 T=512 E=256 H=1024 (round 18).
// Persistent kernel: 256 blocks x 512 threads (8 waves, fused dual-layer).
// Per phase p: L0 (t=p): z0=[x_p;h0(p-1)]@W0 -> h0(p)
//             L1 (t=p-1): z1=[h0(p-1);h1(p-2)]@W1 -> h1(p-1)
// NUMERICS (r13-r17 verified, absmax 2.44e-4): W fp16 LDS-resident (104 KB),
// h fp16 planes, 1 MFMA/kt (mfma_f32_16x16x32_f16), fp32 cell in registers.
// r18 — DELETE the dist + XCD-barrier spine:
//  - h lives in ONE shared rep buffer, 2-parity ping-pong (read slot p&1,
//    write slot (p+1)&1); cells store sc0 sc1 (LLC write-through).
//  - after the global barrier each block invalidates L2+L1 (buffer_inv sc1 ;
//    buffer_inv — the device-fence pair), then GEMM uses PLAIN A-loads: the
//    per-XCD L2 refetches each line once per XCD = automatic replica dedup.
//  - every global store in the persistent kernel is sc0 sc1 (no dirty L2).
// Single tree global barrier per phase (LLC flags, r15/r17-proven), X-part
// GEMM hoisted into the barrier window, 2-deep x 8-frag A prefetch, zb dbuf.
// HARD RULE (r9+r16): all inter-block FLAGS are LLC (sc0 sc1).
// ---------------------------------------------------------------------------

namespace {
constexpr int NBLK = 256, THREADS = 512;
constexpr int KT0B = 40;           // L0 k-tiles of 32 (K=1280): 8 X + 32 D
constexpr int KT1B = 64;           // L1 k-tiles of 32 (K=2048): 32 D + 32 H1
constexpr int NPH = 513;
constexpr int HPS = 128 * 1024;    // u16 elems per h plane (per layer)
constexpr int SPIN_CAP = 2000000;
// flag slots (u32 index into ctr[2048], zeroed per launch) — ALL LLC
constexpr int F_CREG  = 0;         // 8 x 16 (boot atomics)
constexpr int F_BOOT  = 128;
constexpr int F_GARR  = 256;       // 8 x 64 global-arrive per XCD
constexpr int F_XDONE = 768;       // 8 x 16 XCD-done
}

typedef _Float16 f16x8 __attribute__((ext_vector_type(8)));
typedef float f32x4 __attribute__((ext_vector_type(4)));
typedef unsigned u32x4 __attribute__((ext_vector_type(4)));

__host__ __device__ __forceinline__ int fswz(int kk) {   // frag order within 32
  return ((kk & 15) >> 2) * 8 + (kk >> 4) * 4 + (kk & 3);
}

__device__ __forceinline__ float sigm(float x) { return 1.0f / (1.0f + __expf(-x)); }
__device__ __forceinline__ float tanh_f(float x) {
  float e = __expf(-2.0f * fabsf(x));
  float r = (1.0f - e) / (1.0f + e);
  return x >= 0.0f ? r : -r;
}
__device__ __forceinline__ unsigned short f2h(float f) {
  _Float16 h = (_Float16)f;
  return __builtin_bit_cast(unsigned short, h);
}

// ---- LLC-coherent ops (bypass L1+L2) --------------------------------------
__device__ __forceinline__ int load_i32_llc(const int* p) {
  int v;
  asm volatile("global_load_dword %0, %1, off sc0 sc1\n\ts_waitcnt vmcnt(0)"
               : "=v"(v) : "v"(p) : "memory");
  return v;
}
__device__ __forceinline__ void vm_wait0() {
  asm volatile("s_waitcnt vmcnt(0)" ::: "memory");
  __builtin_amdgcn_sched_barrier(0);
}
__device__ __forceinline__ void store_u32_llc(unsigned* p, unsigned v) {
  asm volatile("global_store_dword %0, %1, off sc0 sc1" :: "v"(p), "v"(v) : "memory");
}
__device__ __forceinline__ void store_u16_llc(unsigned short* p, unsigned short v) {
  asm volatile("global_store_short %0, %1, off sc0 sc1" :: "v"(p), "v"(v) : "memory");
}
__device__ __forceinline__ void store_f32_llc(float* p, float v) {
  asm volatile("global_store_dword %0, %1, off sc0 sc1" :: "v"(p), "v"(v) : "memory");
}
__device__ __forceinline__ void inv_l2_l1() {
  asm volatile("buffer_inv sc1" ::: "memory");   // invalidate L2 (clean lines)
  asm volatile("buffer_inv" ::: "memory");       // invalidate L1
}
__device__ __forceinline__ int xcc_id() {
  int x;
  asm("s_getreg_b32 %0, hwreg(HW_REG_XCC_ID)" : "=s"(x));
  return x & 7;
}
__device__ __forceinline__ int spin_ge(int* p, int target) {
  for (int it = 0; it < SPIN_CAP; ++it) {
    if (load_i32_llc(p) >= target) return 1;
    __builtin_amdgcn_s_sleep(1);
  }
  return 0;
}
__device__ __forceinline__ f16x8 ash(u32x4 v) { return __builtin_bit_cast(f16x8, v); }
__device__ __forceinline__ f16x8 ash4(uint4 v) { return __builtin_bit_cast(f16x8, v); }

#define MFMA1(acc, ah, bh)                                                    \
  acc = __builtin_amdgcn_mfma_f32_16x16x32_f16(ah, bh, acc, 0, 0, 0);

// ======================= prep kernels =====================================

__global__ void prep_sort(const int* __restrict__ lens, int* __restrict__ perm,
                          int* __restrict__ lenS, int* __restrict__ ncnt) {
  __shared__ int k_[128], p_[128];
  const int tid = threadIdx.x;
  if (tid < 128) { k_[tid] = (lens[tid] << 8) | (127 - tid); p_[tid] = tid; }
  __syncthreads();
  for (int ph = 0; ph < 128; ++ph) {
    if (tid < 64) {
      int a = 2 * tid + (ph & 1), b = a + 1;
      if (b < 128 && k_[a] < k_[b]) {
        int tk = k_[a]; k_[a] = k_[b]; k_[b] = tk;
        int tp = p_[a]; p_[a] = p_[b]; p_[b] = tp;
      }
    }
    __syncthreads();
  }
  if (tid < 128) { perm[tid] = p_[tid]; lenS[tid] = k_[tid] >> 8; }
  if (tid < 512) {
    int c = 0;
    for (int i = 0; i < 128; ++i) c += ((k_[i] >> 8) > tid) ? 1 : 0;
    ncnt[tid] = c;
  }
}

// emb -> single fp16 plane, fragment-interleaved order
__global__ void prep_emb(const float* __restrict__ emb,
                         unsigned short* __restrict__ ef) {
  int i = blockIdx.x * 256 + threadIdx.x;   // 32768
  int row = i >> 8, e = i & 255;
  int pos = row * 256 + (e >> 5) * 32 + fswz(e & 31);
  ef[pos] = f2h(emb[i]);
}

// W[k][4096] -> per-block fp16 frag slabs: e = (blk*KT + kt)*64 + lane.
__global__ void prep_wslab(const float* __restrict__ W, uint4* __restrict__ Whi,
                           int KT) {
  int e = blockIdx.x * 256 + threadIdx.x;
  int lane = e & 63;
  int kt = (e >> 6) % KT;
  int blk = e / (64 * KT);
  int cf = lane & 15;
  int g = cf & 3, ul = cf >> 2;
  int col = g * 1024 + blk * 4 + ul;
  int kbase = kt * 32 + ((lane >> 4) & 3) * 4;
  unsigned hi[8];
#pragma unroll
  for (int j = 0; j < 8; ++j) {
    int k = kbase + (j & 3) + 16 * (j >> 2);
    float f = W[(size_t)k * 4096 + col];
    hi[j] = __builtin_bit_cast(unsigned short, (_Float16)f);
  }
  uint4 vh;
  vh.x = hi[0] | (hi[1] << 16); vh.y = hi[2] | (hi[3] << 16);
  vh.z = hi[4] | (hi[5] << 16); vh.w = hi[6] | (hi[7] << 16);
  Whi[e] = vh;
}

// ======================= persistent kernel =================================

__global__ __launch_bounds__(THREADS, 1) void lstm_persist(
    const int* __restrict__ ib,
    const float* __restrict__ bias0, const float* __restrict__ bias1,
    const uint4* __restrict__ Whi0g, const uint4* __restrict__ Whi1g,
    const unsigned short* __restrict__ embF,
    const int* __restrict__ perm, const int* __restrict__ lenS,
    const int* __restrict__ ncnt,
    unsigned short* rep,    // [2 parity][2 layer][128][1024] f16 frag-order
    int* ctr, float* __restrict__ out) {
  const int bid = blockIdx.x;
  const int tid = threadIdx.x;
  const int w = tid >> 6;                 // wave 0..7 -> rows w*16..+15
  const int lane = tid & 63;
  const int lr = lane & 15;
  const int lg4 = ((lane >> 4) & 3) * 4;
  const int slotE = ((lane >> 4) & 3) * 8;  // frag u16 offset within 32-group
  const int arow = w * 16 + lr;           // GEMM A row for this lane
  const int srow = tid >> 2;              // cell row 0..127
  const int cu = tid & 3;                 // cell unit 0..3
  const int ug = bid * 4 + cu;            // global unit
  const int fpos = (ug >> 5) * 32 + fswz(ug & 31);
  const int permA = perm[arow];
  const int cperm = perm[srow];
  const int clen = lenS[srow];

  __shared__ uint4 Wh0[KT0B * 64];              // 40 KB
  __shared__ uint4 Wh1[KT1B * 64];              // 64 KB
  __shared__ float zb[2][128][17];              // 17 KB (dbuf: L0, L1)
  __shared__ int s_x, s_rk, s_R, s_pres, s_ok;

  // ---- one-time: W fp16 slabs -> LDS (fully resident) ----
  {
    const uint4* s0 = Whi0g + (size_t)bid * (KT0B * 64);
    for (int i = tid; i < KT0B * 64; i += THREADS) Wh0[i] = s0[i];
    const uint4* s1 = Whi1g + (size_t)bid * (KT1B * 64);
    for (int i = tid; i < KT1B * 64; i += THREADS) Wh1[i] = s1[i];
  }

  float bz0[4], bz1[4];
#pragma unroll
  for (int g = 0; g < 4; ++g) {
    bz0[g] = bias0[g * 1024 + ug];
    bz1[g] = bias1[g * 1024 + ug];
  }
  float c0r = 0.0f, c1r = 0.0f;

  // ---- bootstrap (LLC atomics, once) ----
  if (tid == 0) {
    s_ok = 1;
    int x = xcc_id();
    s_x = x;
    s_rk = atomicAdd(&ctr[F_CREG + x * 16], 1);
    vm_wait0();
    atomicAdd(&ctr[F_BOOT], 1);
    if (!spin_ge(&ctr[F_BOOT], NBLK)) s_ok = 0;
    int Rv = 1, pres = 0;
    for (int i = 0; i < 8; ++i) {
      int r = load_i32_llc(&ctr[F_CREG + i * 16]);
      if (r > 0) pres |= (1 << i);
      if (i == s_x) Rv = r;
    }
    s_R = Rv;
    s_pres = pres;
  }
  __syncthreads();
  const int xcd = s_x, rk = s_rk, R = s_R, pres = s_pres;
  if (!s_ok) return;

  // ---- prologue: X-part GEMM for phase 0 ----
  f32x4 acc0 = (f32x4){0.f, 0.f, 0.f, 0.f};
  if (w * 16 < ncnt[0]) {
    const unsigned short* ef = embF + ib[(size_t)permA * 512] * 256;
#pragma unroll
    for (int kt = 0; kt < 8; ++kt) {
      const f16x8 ah = ash(*(const u32x4*)(ef + kt * 32 + slotE));
      MFMA1(acc0, ah, ash4(Wh0[kt * 64 + lane]))
    }
  }

  for (int p = 0; p < NPH; ++p) {
    const int nact0 = (p < 512) ? ncnt[p] : 0;
    const int nact1 = (p >= 1) ? ncnt[p - 1] : 0;
    const bool doL0 = (p < 512) && (w * 16 < nact0);
    const bool doL1 = (p >= 1) && (w * 16 < nact1);

    f32x4 acc1 = (f32x4){0.f, 0.f, 0.f, 0.f};

    // slot pointers: read slot p&1, write slot (p+1)&1
    const unsigned short* A0 = rep + (size_t)((p & 1) * 2 + 0) * HPS + (size_t)arow * 1024;
    const unsigned short* A1 = rep + (size_t)((p & 1) * 2 + 1) * HPS + (size_t)arow * 1024;
    unsigned short* w0p = rep + (size_t)(((p + 1) & 1) * 2 + 0) * HPS;
    unsigned short* w1p = rep + (size_t)(((p + 1) & 1) * 2 + 1) * HPS;

    // ---- (A) main GEMM: 2-deep x 8-frag A-prefetch, PLAIN loads (L2) ----
    if (doL0 || doL1) {
      u32x4 a[2][8];
#pragma unroll
      for (int i = 0; i < 8; ++i) a[0][i] = *(const u32x4*)(A0 + i * 32 + slotE);
#pragma unroll
      for (int g = 0; g < 4; ++g) {
        const int cb = g & 1;
        if (g < 3) {
#pragma unroll
          for (int i = 0; i < 8; ++i)
            a[cb ^ 1][i] = *(const u32x4*)(A0 + ((g + 1) * 8 + i) * 32 + slotE);
        } else if (doL1) {
#pragma unroll
          for (int i = 0; i < 8; ++i)
            a[cb ^ 1][i] = *(const u32x4*)(A1 + i * 32 + slotE);
        }
#pragma unroll
        for (int i = 0; i < 8; ++i) {
          const int q = g * 8 + i;
          const f16x8 ah = ash(a[cb][i]);
          if (doL0) { MFMA1(acc0, ah, ash4(Wh0[(8 + q) * 64 + lane])) }
          if (doL1) { MFMA1(acc1, ah, ash4(Wh1[q * 64 + lane])) }
        }
      }
      if (doL1) {
#pragma unroll
        for (int g = 0; g < 4; ++g) {
          const int cb = g & 1;
          if (g < 3) {
#pragma unroll
            for (int i = 0; i < 8; ++i)
              a[cb ^ 1][i] = *(const u32x4*)(A1 + ((g + 1) * 8 + i) * 32 + slotE);
          }
#pragma unroll
          for (int i = 0; i < 8; ++i) {
            const int q = g * 8 + i;
            const f16x8 ah = ash(a[cb][i]);
            MFMA1(acc1, ah, ash4(Wh1[(32 + q) * 64 + lane]))
          }
        }
      }
    }

    // ---- (B) z exchange (zb dbuf, ONE sync) + cells (sc0 sc1 stores) ----
    if (doL0) {
#pragma unroll
      for (int rr = 0; rr < 4; ++rr) zb[0][w * 16 + lg4 + rr][lr] = acc0[rr];
    }
    if (doL1) {
#pragma unroll
      for (int rr = 0; rr < 4; ++rr) zb[1][w * 16 + lg4 + rr][lr] = acc1[rr];
    }
    __syncthreads();
    if (p < 512 && p < clen) {            // L0 cell, t = p -> h0(p)
      const float zi = zb[0][srow][cu * 4 + 0] + bz0[0];
      const float zj = zb[0][srow][cu * 4 + 1] + bz0[1];
      const float zf = zb[0][srow][cu * 4 + 2] + bz0[2];
      const float zo = zb[0][srow][cu * 4 + 3] + bz0[3];
      const float nc = c0r * sigm(zf + 1.0f) + sigm(zi) * tanh_f(zj);
      const float nh = tanh_f(nc) * sigm(zo);
      c0r = nc;
      store_u16_llc(&w0p[(size_t)srow * 1024 + fpos], f2h(nh));
    }
    if (p >= 1 && (p - 1) < clen) {       // L1 cell, t = p-1 -> h1(p-1)
      const float zi = zb[1][srow][cu * 4 + 0] + bz1[0];
      const float zj = zb[1][srow][cu * 4 + 1] + bz1[1];
      const float zf = zb[1][srow][cu * 4 + 2] + bz1[2];
      const float zo = zb[1][srow][cu * 4 + 3] + bz1[3];
      const float nc = c1r * sigm(zf + 1.0f) + sigm(zi) * tanh_f(zj);
      const float nh = tanh_f(nc) * sigm(zo);
      c1r = nc;
      store_u16_llc(&w1p[(size_t)srow * 1024 + fpos], f2h(nh));
      if (p - 1 == clen - 1) store_f32_llc(&out[(size_t)cperm * 1024 + ug], nh);
    }

    // ---- (C) TREE global barrier (LLC); X-part(p+1) hidden in window ----
    vm_wait0();                           // h/out stores LLC-visible
    __syncthreads();
    if (tid == 0) store_u32_llc((unsigned*)&ctr[F_GARR + xcd * 64 + rk], p + 1);

    // X-part GEMM for phase p+1 (constants only: emb + LDS W0)
    acc0 = (f32x4){0.f, 0.f, 0.f, 0.f};
    if (p + 1 < 512 && (w * 16 < ncnt[p + 1])) {
      const unsigned short* ef = embF + ib[(size_t)permA * 512 + (p + 1)] * 256;
#pragma unroll
      for (int kt = 0; kt < 8; ++kt) {
        const f16x8 ah = ash(*(const u32x4*)(ef + kt * 32 + slotE));
        MFMA1(acc0, ah, ash4(Wh0[kt * 64 + lane]))
      }
    }

    if (rk == 0) {                        // XCD leader block
      if (tid < 64 && tid < R) {
        if (!spin_ge(&ctr[F_GARR + xcd * 64 + tid], p + 1)) s_ok = 0;
      }
      __syncthreads();
      if (tid == 0) store_u32_llc((unsigned*)&ctr[F_XDONE + xcd * 16], p + 1);
    }
    if (tid < 8 && ((pres >> tid) & 1)) {
      if (!spin_ge(&ctr[F_XDONE + tid * 16], p + 1)) s_ok = 0;
    }
    __syncthreads();
    if (!s_ok) break;
    inv_l2_l1();   // drop stale clean replica lines; plain loads refetch fresh
  }
}

// ======================= host launch =======================================

extern "C" void kernel_launch(void* const* d_in, const int* in_sizes, int n_in,
                              void* d_out, int out_size, void* d_ws, size_t ws_size,
                              hipStream_t stream) {
  const int*   ib   = (const int*)d_in[0];
  const int*   lens = (const int*)d_in[1];
  const float* emb  = (const float*)d_in[2];
  const float* W0   = (const float*)d_in[3];
  const float* b0   = (const float*)d_in[4];
  const float* W1   = (const float*)d_in[5];
  const float* b1   = (const float*)d_in[6];
  (void)in_sizes; (void)n_in; (void)out_size; (void)ws_size;

  char* ws = (char*)d_ws;
  size_t off = 0;
  auto alloc = [&](size_t bytes) { char* q = ws + off; off += (bytes + 255) & ~(size_t)255; return q; };

  int*            ctr  = (int*)alloc(8192);
  unsigned short* rep  = (unsigned short*)alloc((size_t)2 * 2 * HPS * 2);  // 1 MB
  const size_t zero_bytes = off;          // ctr + rep (phase-0 reads zeros)
  unsigned short* embF = (unsigned short*)alloc(128 * 256 * 2);
  int*            perm = (int*)alloc(4096);
  int*            lenS = perm + 128;
  int*            ncnt = perm + 256;
  uint4*          Whi0 = (uint4*)alloc((size_t)NBLK * KT0B * 64 * 16);
  uint4*          Whi1 = (uint4*)alloc((size_t)NBLK * KT1B * 64 * 16);

  hipMemsetAsync(d_ws, 0, zero_bytes, stream);
  prep_sort<<<1, 512, 0, stream>>>(lens, perm, lenS, ncnt);
  prep_emb<<<128, 256, 0, stream>>>(emb, embF);
  prep_wslab<<<(NBLK * KT0B * 64) / 256, 256, 0, stream>>>(W0, Whi0, KT0B);
  prep_wslab<<<(NBLK * KT1B * 64) / 256, 256, 0, stream>>>(W1, Whi1, KT1B);
  lstm_persist<<<NBLK, THREADS, 0, stream>>>(
      ib, b0, b1, Whi0, Whi1, embF,
      perm, lenS, ncnt, rep, ctr, (float*)d_out);
}

// Round 19
// 7410.220 us; speedup vs baseline: 1.8504x; 1.8504x over previous
//
#include <hip/hip_runtime.h>

// ---------------------------------------------------------------------------
// 2-layer LSTM encoder, B=128 T=512 E=256 H=1024 (round 19).
// Persistent kernel: 256 blocks x 512 threads (8 waves, fused dual-layer).
// Per phase p: L0 (t=p): z0=[x_p;h0(p-1)]@W0 -> h0(p)
//             L1 (t=p-1): z1=[h0(p-1);h1(p-2)]@W1 -> h1(p-1)
// NUMERICS (r13-r17 verified, absmax 2.44e-4): W fp16 LDS-resident (104 KB),
// h fp16 planes, 1 MFMA/kt (mfma_f32_16x16x32_f16), fp32 cell in registers.
// r19 = r17 (verified 7.47 ms best) + s_setprio(1) around GEMM MFMA clusters.
// Structure: per-XCD replica dist, flat XCD barrier + inv_l1, 2-deep x 8-frag
// A-prefetch GEMM, zb-dbuf single-sync cells, TREE global barrier with
// X-part(p+1) hoisted into the window. ALL flags LLC sc0 sc1 (r9/r16 rule);
// whole-L2 invalidation is a proven regression (r18).
// ---------------------------------------------------------------------------

namespace {
constexpr int NBLK = 256, THREADS = 512;
constexpr int KT0B = 40;           // L0 k-tiles of 32 (K=1280): 8 X + 32 D
constexpr int KT1B = 64;           // L1 k-tiles of 32 (K=2048): 32 D + 32 H1
constexpr int NPH = 513;
constexpr int HPS = 128 * 1024;    // u16 elems per h plane (per layer)
constexpr int SPIN_CAP = 2000000;
// flag slots (u32 index into ctr[2048], zeroed per launch) — ALL LLC
constexpr int F_CREG  = 0;         // 8 x 16 (boot atomics)
constexpr int F_BOOT  = 128;
constexpr int F_GARR  = 256;       // 8 x 64 global-arrive per XCD
constexpr int F_XDONE = 768;       // 8 x 16 XCD-done
constexpr int F_XARR  = 1024;      // 8 x 64 mid-phase XCD arrive
}

typedef _Float16 f16x8 __attribute__((ext_vector_type(8)));
typedef float f32x4 __attribute__((ext_vector_type(4)));
typedef unsigned u32x4 __attribute__((ext_vector_type(4)));

__host__ __device__ __forceinline__ int fswz(int kk) {   // frag order within 32
  return ((kk & 15) >> 2) * 8 + (kk >> 4) * 4 + (kk & 3);
}

__device__ __forceinline__ float sigm(float x) { return 1.0f / (1.0f + __expf(-x)); }
__device__ __forceinline__ float tanh_f(float x) {
  float e = __expf(-2.0f * fabsf(x));
  float r = (1.0f - e) / (1.0f + e);
  return x >= 0.0f ? r : -r;
}
__device__ __forceinline__ unsigned short f2h(float f) {
  _Float16 h = (_Float16)f;
  return __builtin_bit_cast(unsigned short, h);
}

// ---- LLC-coherent ops (bypass L1+L2) --------------------------------------
__device__ __forceinline__ int load_i32_llc(const int* p) {
  int v;
  asm volatile("global_load_dword %0, %1, off sc0 sc1\n\ts_waitcnt vmcnt(0)"
               : "=v"(v) : "v"(p) : "memory");
  return v;
}
__device__ __forceinline__ uint4 llc_load_issue(const unsigned* p) {
  uint4 v;
  asm volatile("global_load_dwordx4 %0, %1, off sc0 sc1" : "=v"(v) : "v"(p));
  return v;
}
__device__ __forceinline__ void vm_wait0() {
  asm volatile("s_waitcnt vmcnt(0)" ::: "memory");
  __builtin_amdgcn_sched_barrier(0);
}
__device__ __forceinline__ void store_u32_llc(unsigned* p, unsigned v) {
  asm volatile("global_store_dword %0, %1, off sc0 sc1" :: "v"(p), "v"(v) : "memory");
}
__device__ __forceinline__ void store_u16_llc(unsigned short* p, unsigned short v) {
  asm volatile("global_store_short %0, %1, off sc0 sc1" :: "v"(p), "v"(v) : "memory");
}
__device__ __forceinline__ void inv_l1() {
  asm volatile("buffer_inv" ::: "memory");
}
__device__ __forceinline__ int xcc_id() {
  int x;
  asm("s_getreg_b32 %0, hwreg(HW_REG_XCC_ID)" : "=s"(x));
  return x & 7;
}
__device__ __forceinline__ int spin_ge(int* p, int target) {
  for (int it = 0; it < SPIN_CAP; ++it) {
    if (load_i32_llc(p) >= target) return 1;
    __builtin_amdgcn_s_sleep(1);
  }
  return 0;
}
__device__ __forceinline__ f16x8 ash(u32x4 v) { return __builtin_bit_cast(f16x8, v); }
__device__ __forceinline__ f16x8 ash4(uint4 v) { return __builtin_bit_cast(f16x8, v); }

#define MFMA1(acc, ah, bh)                                                    \
  acc = __builtin_amdgcn_mfma_f32_16x16x32_f16(ah, bh, acc, 0, 0, 0);

// ======================= prep kernels =====================================

__global__ void prep_sort(const int* __restrict__ lens, int* __restrict__ perm,
                          int* __restrict__ lenS, int* __restrict__ ncnt) {
  __shared__ int k_[128], p_[128];
  const int tid = threadIdx.x;
  if (tid < 128) { k_[tid] = (lens[tid] << 8) | (127 - tid); p_[tid] = tid; }
  __syncthreads();
  for (int ph = 0; ph < 128; ++ph) {
    if (tid < 64) {
      int a = 2 * tid + (ph & 1), b = a + 1;
      if (b < 128 && k_[a] < k_[b]) {
        int tk = k_[a]; k_[a] = k_[b]; k_[b] = tk;
        int tp = p_[a]; p_[a] = p_[b]; p_[b] = tp;
      }
    }
    __syncthreads();
  }
  if (tid < 128) { perm[tid] = p_[tid]; lenS[tid] = k_[tid] >> 8; }
  if (tid < 512) {
    int c = 0;
    for (int i = 0; i < 128; ++i) c += ((k_[i] >> 8) > tid) ? 1 : 0;
    ncnt[tid] = c;
  }
}

// emb -> single fp16 plane, fragment-interleaved order
__global__ void prep_emb(const float* __restrict__ emb,
                         unsigned short* __restrict__ ef) {
  int i = blockIdx.x * 256 + threadIdx.x;   // 32768
  int row = i >> 8, e = i & 255;
  int pos = row * 256 + (e >> 5) * 32 + fswz(e & 31);
  ef[pos] = f2h(emb[i]);
}

// W[k][4096] -> per-block fp16 frag slabs: e = (blk*KT + kt)*64 + lane.
__global__ void prep_wslab(const float* __restrict__ W, uint4* __restrict__ Whi,
                           int KT) {
  int e = blockIdx.x * 256 + threadIdx.x;
  int lane = e & 63;
  int kt = (e >> 6) % KT;
  int blk = e / (64 * KT);
  int cf = lane & 15;
  int g = cf & 3, ul = cf >> 2;
  int col = g * 1024 + blk * 4 + ul;
  int kbase = kt * 32 + ((lane >> 4) & 3) * 4;
  unsigned hi[8];
#pragma unroll
  for (int j = 0; j < 8; ++j) {
    int k = kbase + (j & 3) + 16 * (j >> 2);
    float f = W[(size_t)k * 4096 + col];
    hi[j] = __builtin_bit_cast(unsigned short, (_Float16)f);
  }
  uint4 vh;
  vh.x = hi[0] | (hi[1] << 16); vh.y = hi[2] | (hi[3] << 16);
  vh.z = hi[4] | (hi[5] << 16); vh.w = hi[6] | (hi[7] << 16);
  Whi[e] = vh;
}

// ======================= persistent kernel =================================

__global__ __launch_bounds__(THREADS, 1) void lstm_persist(
    const int* __restrict__ ib,
    const float* __restrict__ bias0, const float* __restrict__ bias1,
    const uint4* __restrict__ Whi0g, const uint4* __restrict__ Whi1g,
    const unsigned short* __restrict__ embF,
    const int* __restrict__ perm, const int* __restrict__ lenS,
    const int* __restrict__ ncnt,
    unsigned short* hg0, unsigned short* hg1,   // [3][128][1024] f16 frag-order
    unsigned short* rep,                        // [8][2][128][1024] f16
    int* ctr, float* __restrict__ out) {
  const int bid = blockIdx.x;
  const int tid = threadIdx.x;
  const int w = tid >> 6;                 // wave 0..7 -> rows w*16..+15
  const int lane = tid & 63;
  const int lr = lane & 15;
  const int lg4 = ((lane >> 4) & 3) * 4;
  const int slotE = ((lane >> 4) & 3) * 8;  // frag u16 offset within 32-group
  const int arow = w * 16 + lr;           // GEMM A row for this lane
  const int srow = tid >> 2;              // cell row 0..127
  const int cu = tid & 3;                 // cell unit 0..3
  const int ug = bid * 4 + cu;            // global unit
  const int fpos = (ug >> 5) * 32 + fswz(ug & 31);
  const int permA = perm[arow];
  const int cperm = perm[srow];
  const int clen = lenS[srow];

  __shared__ uint4 Wh0[KT0B * 64];              // 40 KB
  __shared__ uint4 Wh1[KT1B * 64];              // 64 KB
  __shared__ float zb[2][128][17];              // 17 KB (dbuf: L0, L1)
  __shared__ int s_x, s_rk, s_R, s_pres, s_ok;

  // ---- one-time: W fp16 slabs -> LDS (fully resident) ----
  {
    const uint4* s0 = Whi0g + (size_t)bid * (KT0B * 64);
    for (int i = tid; i < KT0B * 64; i += THREADS) Wh0[i] = s0[i];
    const uint4* s1 = Whi1g + (size_t)bid * (KT1B * 64);
    for (int i = tid; i < KT1B * 64; i += THREADS) Wh1[i] = s1[i];
  }

  float bz0[4], bz1[4];
#pragma unroll
  for (int g = 0; g < 4; ++g) {
    bz0[g] = bias0[g * 1024 + ug];
    bz1[g] = bias1[g * 1024 + ug];
  }
  float c0r = 0.0f, c1r = 0.0f;

  // ---- bootstrap (LLC atomics, once) ----
  if (tid == 0) {
    s_ok = 1;
    int x = xcc_id();
    s_x = x;
    s_rk = atomicAdd(&ctr[F_CREG + x * 16], 1);
    vm_wait0();
    atomicAdd(&ctr[F_BOOT], 1);
    if (!spin_ge(&ctr[F_BOOT], NBLK)) s_ok = 0;
    int Rv = 1, pres = 0;
    for (int i = 0; i < 8; ++i) {
      int r = load_i32_llc(&ctr[F_CREG + i * 16]);
      if (r > 0) pres |= (1 << i);
      if (i == s_x) Rv = r;
    }
    s_R = Rv;
    s_pres = pres;
  }
  __syncthreads();
  const int xcd = s_x, rk = s_rk, R = s_R, pres = s_pres;
  if (!s_ok) return;

  unsigned short* repB = rep + (size_t)xcd * 2 * HPS;
  const unsigned short* A0 = repB + (size_t)arow * 1024;          // h0 plane
  const unsigned short* A1 = repB + HPS + (size_t)arow * 1024;    // h1 plane

  // distribution role: plane pl (0=h0,1=h1), row-offset bit, 16B chunk
  const int pl = tid >> 8;                // 0..1
  const int rowoff = (tid >> 7) & 1;      // row pair bit
  const int ch = (tid & 127) * 8;         // u16 offset in row
  unsigned short* dp = repB + pl * HPS;

  // ---- prologue: X-part GEMM for phase 0 ----
  f32x4 acc0 = (f32x4){0.f, 0.f, 0.f, 0.f};
  if (w * 16 < ncnt[0]) {
    const unsigned short* ef = embF + ib[(size_t)permA * 512] * 256;
#pragma unroll
    for (int kt = 0; kt < 8; ++kt) {
      const f16x8 ah = ash(*(const u32x4*)(ef + kt * 32 + slotE));
      MFMA1(acc0, ah, ash4(Wh0[kt * 64 + lane]))
    }
  }

  for (int p = 0; p < NPH; ++p) {
    const int nact0 = (p < 512) ? ncnt[p] : 0;
    const int nact1 = (p >= 1) ? ncnt[p - 1] : 0;
    const bool doL0 = (p < 512) && (w * 16 < nact0);
    const bool doL1 = (p >= 1) && (w * 16 < nact1);
    const int ncopy = ncnt[p == 0 ? 0 : p - 1];

    f32x4 acc1 = (f32x4){0.f, 0.f, 0.f, 0.f};

    // ---- (A) dist: issue LLC loads, wait, store into replica ----
    {
      const unsigned short* sp =
          (pl == 0) ? (hg0 + (size_t)((p + 2) % 3) * HPS)
                    : (hg1 + (size_t)((p + 1) % 3) * HPS);
      const int step = 2 * R;
      const int dr0 = 2 * rk + rowoff;
      const int dr1 = dr0 + step, dr2 = dr0 + 2 * step, dr3 = dr0 + 3 * step;
      uint4 dv0, dv1, dv2, dv3;
      if (dr0 < ncopy) dv0 = llc_load_issue((const unsigned*)(sp + dr0 * 1024 + ch));
      if (dr1 < ncopy) dv1 = llc_load_issue((const unsigned*)(sp + dr1 * 1024 + ch));
      if (dr2 < ncopy) dv2 = llc_load_issue((const unsigned*)(sp + dr2 * 1024 + ch));
      if (dr3 < ncopy) dv3 = llc_load_issue((const unsigned*)(sp + dr3 * 1024 + ch));
      vm_wait0();
      if (dr0 < ncopy) *(uint4*)(dp + dr0 * 1024 + ch) = dv0;
      if (dr1 < ncopy) *(uint4*)(dp + dr1 * 1024 + ch) = dv1;
      if (dr2 < ncopy) *(uint4*)(dp + dr2 * 1024 + ch) = dv2;
      if (dr3 < ncopy) *(uint4*)(dp + dr3 * 1024 + ch) = dv3;
      for (int r = dr0 + 4 * step; r < ncopy; r += step) {
        uint4 v = llc_load_issue((const unsigned*)(sp + r * 1024 + ch));
        vm_wait0();
        *(uint4*)(dp + r * 1024 + ch) = v;
      }
    }
    __syncthreads();                      // dist stores drained (vmcnt(0))

    // ---- (B) XCD barrier (flat LLC flags, stride-64 regions) ----
    if (tid == 0) store_u32_llc((unsigned*)&ctr[F_XARR + xcd * 64 + rk], p + 1);
    if (tid < 64 && tid < R) {
      if (!spin_ge(&ctr[F_XARR + xcd * 64 + tid], p + 1)) s_ok = 0;
    }
    __syncthreads();
    if (!s_ok) break;
    inv_l1();                             // fresh L1 view of replica

    // ---- (C) main GEMM: 2-deep x 8-frag A-prefetch pipeline (setprio) ----
    if (doL0 || doL1) {
      u32x4 a[2][8];
#pragma unroll
      for (int i = 0; i < 8; ++i) a[0][i] = *(const u32x4*)(A0 + i * 32 + slotE);
#pragma unroll
      for (int g = 0; g < 4; ++g) {
        const int cb = g & 1;
        if (g < 3) {
#pragma unroll
          for (int i = 0; i < 8; ++i)
            a[cb ^ 1][i] = *(const u32x4*)(A0 + ((g + 1) * 8 + i) * 32 + slotE);
        } else if (doL1) {
#pragma unroll
          for (int i = 0; i < 8; ++i)
            a[cb ^ 1][i] = *(const u32x4*)(A1 + i * 32 + slotE);
        }
        __builtin_amdgcn_s_setprio(1);
#pragma unroll
        for (int i = 0; i < 8; ++i) {
          const int q = g * 8 + i;
          const f16x8 ah = ash(a[cb][i]);
          if (doL0) { MFMA1(acc0, ah, ash4(Wh0[(8 + q) * 64 + lane])) }
          if (doL1) { MFMA1(acc1, ah, ash4(Wh1[q * 64 + lane])) }
        }
        __builtin_amdgcn_s_setprio(0);
      }
      if (doL1) {
#pragma unroll
        for (int g = 0; g < 4; ++g) {
          const int cb = g & 1;
          if (g < 3) {
#pragma unroll
            for (int i = 0; i < 8; ++i)
              a[cb ^ 1][i] = *(const u32x4*)(A1 + ((g + 1) * 8 + i) * 32 + slotE);
          }
          __builtin_amdgcn_s_setprio(1);
#pragma unroll
          for (int i = 0; i < 8; ++i) {
            const int q = g * 8 + i;
            const f16x8 ah = ash(a[cb][i]);
            MFMA1(acc1, ah, ash4(Wh1[(32 + q) * 64 + lane]))
          }
          __builtin_amdgcn_s_setprio(0);
        }
      }
    }

    // ---- (D) z exchange (zb dbuf, ONE sync) + cells ----
    if (doL0) {
#pragma unroll
      for (int rr = 0; rr < 4; ++rr) zb[0][w * 16 + lg4 + rr][lr] = acc0[rr];
    }
    if (doL1) {
#pragma unroll
      for (int rr = 0; rr < 4; ++rr) zb[1][w * 16 + lg4 + rr][lr] = acc1[rr];
    }
    __syncthreads();
    if (p < 512 && p < clen) {            // L0 cell, t = p
      const float zi = zb[0][srow][cu * 4 + 0] + bz0[0];
      const float zj = zb[0][srow][cu * 4 + 1] + bz0[1];
      const float zf = zb[0][srow][cu * 4 + 2] + bz0[2];
      const float zo = zb[0][srow][cu * 4 + 3] + bz0[3];
      const float nc = c0r * sigm(zf + 1.0f) + sigm(zi) * tanh_f(zj);
      const float nh = tanh_f(nc) * sigm(zo);
      c0r = nc;
      store_u16_llc(&hg0[(size_t)(p % 3) * HPS + srow * 1024 + fpos], f2h(nh));
    }
    if (p >= 1 && (p - 1) < clen) {       // L1 cell, t = p-1
      const float zi = zb[1][srow][cu * 4 + 0] + bz1[0];
      const float zj = zb[1][srow][cu * 4 + 1] + bz1[1];
      const float zf = zb[1][srow][cu * 4 + 2] + bz1[2];
      const float zo = zb[1][srow][cu * 4 + 3] + bz1[3];
      const float nc = c1r * sigm(zf + 1.0f) + sigm(zi) * tanh_f(zj);
      const float nh = tanh_f(nc) * sigm(zo);
      c1r = nc;
      store_u16_llc(&hg1[(size_t)((p + 2) % 3) * HPS + srow * 1024 + fpos], f2h(nh));
      if (p - 1 == clen - 1) out[(size_t)cperm * 1024 + ug] = nh;
    }

    // ---- (E) TREE global barrier (LLC); X-part(p+1) hidden in window ----
    vm_wait0();                           // h stores LLC-visible
    __syncthreads();
    if (tid == 0) store_u32_llc((unsigned*)&ctr[F_GARR + xcd * 64 + rk], p + 1);

    // X-part GEMM for phase p+1 (constants only: emb + LDS W0)
    acc0 = (f32x4){0.f, 0.f, 0.f, 0.f};
    if (p + 1 < 512 && (w * 16 < ncnt[p + 1])) {
      const unsigned short* ef = embF + ib[(size_t)permA * 512 + (p + 1)] * 256;
#pragma unroll
      for (int kt = 0; kt < 8; ++kt) {
        const f16x8 ah = ash(*(const u32x4*)(ef + kt * 32 + slotE));
        MFMA1(acc0, ah, ash4(Wh0[kt * 64 + lane]))
      }
    }

    if (rk == 0) {                        // XCD leader block
      if (tid < 64 && tid < R) {
        if (!spin_ge(&ctr[F_GARR + xcd * 64 + tid], p + 1)) s_ok = 0;
      }
      __syncthreads();
      if (tid == 0) store_u32_llc((unsigned*)&ctr[F_XDONE + xcd * 16], p + 1);
    }
    if (tid < 8 && ((pres >> tid) & 1)) {
      if (!spin_ge(&ctr[F_XDONE + tid * 16], p + 1)) s_ok = 0;
    }
    __syncthreads();
    if (!s_ok) break;
  }
}

// ======================= host launch =======================================

extern "C" void kernel_launch(void* const* d_in, const int* in_sizes, int n_in,
                              void* d_out, int out_size, void* d_ws, size_t ws_size,
                              hipStream_t stream) {
  const int*   ib   = (const int*)d_in[0];
  const int*   lens = (const int*)d_in[1];
  const float* emb  = (const float*)d_in[2];
  const float* W0   = (const float*)d_in[3];
  const float* b0   = (const float*)d_in[4];
  const float* W1   = (const float*)d_in[5];
  const float* b1   = (const float*)d_in[6];
  (void)in_sizes; (void)n_in; (void)out_size; (void)ws_size;

  char* ws = (char*)d_ws;
  size_t off = 0;
  auto alloc = [&](size_t bytes) { char* q = ws + off; off += (bytes + 255) & ~(size_t)255; return q; };

  int*            ctr  = (int*)alloc(8192);
  unsigned short* hg0  = (unsigned short*)alloc((size_t)3 * HPS * 2);
  unsigned short* hg1  = (unsigned short*)alloc((size_t)3 * HPS * 2);
  const size_t zero_bytes = off;          // ctr + h planes
  unsigned short* embF = (unsigned short*)alloc(128 * 256 * 2);
  int*            perm = (int*)alloc(4096);
  int*            lenS = perm + 128;
  int*            ncnt = perm + 256;
  unsigned short* rep  = (unsigned short*)alloc((size_t)8 * 2 * HPS * 2);
  uint4*          Whi0 = (uint4*)alloc((size_t)NBLK * KT0B * 64 * 16);
  uint4*          Whi1 = (uint4*)alloc((size_t)NBLK * KT1B * 64 * 16);

  hipMemsetAsync(d_ws, 0, zero_bytes, stream);
  prep_sort<<<1, 512, 0, stream>>>(lens, perm, lenS, ncnt);
  prep_emb<<<128, 256, 0, stream>>>(emb, embF);
  prep_wslab<<<(NBLK * KT0B * 64) / 256, 256, 0, stream>>>(W0, Whi0, KT0B);
  prep_wslab<<<(NBLK * KT1B * 64) / 256, 256, 0, stream>>>(W1, Whi1, KT1B);
  lstm_persist<<<NBLK, THREADS, 0, stream>>>(
      ib, b0, b1, Whi0, Whi1, embF,
      perm, lenS, ncnt, hg0, hg1, rep, ctr, (float*)d_out);
}